// Round 9
// baseline (951.085 us; speedup 1.0000x reference)
//
#include <hip/hip_runtime.h>
#include <cstdint>
#include <cstddef>

#define BB  32
#define FF  10
#define NBN 20
#define HH  128
#define GG  5
#define BSTR (FF*NBN*HH)   // 25600
#define FSTR (NBN*HH)      // 2560
#define XPAD 132           // LDS [b][k] row stride (floats)
#define NCELLS 400
#define SC_SYS __HIP_MEMORY_SCOPE_SYSTEM

struct StageList { int cnt; int cells[20]; };  // packed (r<<16)|(f<<8)|n

__device__ __forceinline__ float sigm(float x) {
  return 1.f / (1.f + __expf(-x));
}
__device__ __forceinline__ float tanh_fast(float x) {
  float e = __expf(-2.f * fabsf(x));
  float t = (1.f - e) / (1.f + e);
  return copysignf(t, x);
}
__device__ __forceinline__ void fma4(float4& a, const float4 w, const float h) {
  a.x = fmaf(w.x, h, a.x); a.y = fmaf(w.y, h, a.y);
  a.z = fmaf(w.z, h, a.z); a.w = fmaf(w.w, h, a.w);
}
__device__ __forceinline__ void add4(float4& a, const float4 b) {
  a.x += b.x; a.y += b.y; a.z += b.z; a.w += b.w;
}

// Boundary vectors (pure functions of inputs).
__global__ void precompute_kernel(
    const float* __restrict__ hid, const float* __restrict__ cell,
    const float* __restrict__ gt,
    float* __restrict__ top_c, float* __restrict__ left_c,
    float* __restrict__ top_h0, float* __restrict__ top_h1,
    float* __restrict__ left_h) {
  int idx = blockIdx.x * 256 + threadIdx.x;
  const int NTOP = BB * NBN * HH;
  const int NLEFT = BB * FF * HH;
  if (idx < NTOP) {
    int h = idx & (HH - 1);
    int n = (idx >> 7) % NBN;
    int b = idx / (HH * NBN);
    const float* hp = hid + (size_t)b * BSTR + n * HH + h;
    const float* cp = cell + (size_t)b * BSTR + n * HH + h;
    float sh = 0.f, sc = 0.f;
#pragma unroll
    for (int f = 0; f < FF; ++f) { sh += hp[f * FSTR]; sc += cp[f * FSTR]; }
    top_c[idx]  = sc * (1.f / FF);
    top_h0[idx] = sh * (1.f / FF);
    top_h1[idx] = (sh + gt[idx]) * (1.f / (FF + 1));
  } else if (idx < NTOP + NLEFT) {
    int j = idx - NTOP;
    int h = j & (HH - 1);
    int f = (j >> 7) % FF;
    int b = j / (HH * FF);
    const float* hp = hid + (size_t)b * BSTR + f * FSTR + h;
    const float* cp = cell + (size_t)b * BSTR + f * FSTR + h;
    float sh = 0.f, sc = 0.f;
#pragma unroll
    for (int n = 0; n < NBN; ++n) { sh += hp[n * HH]; sc += cp[n * HH]; }
    left_c[j] = sc * (1.f / NBN);
    left_h[j] = sh * (1.f / NBN);
  }
}

// Z0 = p.U[0] + bias[0] — dependency-free, 1000 blocks, off the critical path.
__global__ __launch_bounds__(256, 4)
void z0_kernel(const float* __restrict__ p, const float* __restrict__ U,
               const float* __restrict__ bias, float* __restrict__ Z) {
  __shared__ __align__(16) float xs[HH][36];
  const int cell = blockIdx.x / GG, g = blockIdx.x % GG;
  const int f = cell / NBN, n = cell % NBN;
  const int t = threadIdx.x;
  const int cid = t & 31, bq = t >> 5;
  const int cellofs = f * FSTR + n * HH;

  for (int i = t; i < BB * HH; i += 256) {
    int b = i >> 7, k = i & (HH - 1);
    xs[k][b] = p[(size_t)b * BSTR + cellofs + k];
  }
  __syncthreads();

  const float* wu = U + (size_t)cell * (GG * HH * HH) + (size_t)g * HH * HH + cid * 4;
  float4 bv = *(const float4*)(bias + (size_t)cell * (GG * HH) + g * HH + cid * 4);
  float4 acc[4];
#pragma unroll
  for (int j = 0; j < 4; ++j) acc[j] = bv;

#pragma unroll 4
  for (int k = 0; k < HH; ++k) {
    float4 w = *(const float4*)(wu + (size_t)k * HH);
    float4 x = *(const float4*)&xs[k][bq * 4];
    fma4(acc[0], w, x.x); fma4(acc[1], w, x.y);
    fma4(acc[2], w, x.z); fma4(acc[3], w, x.w);
  }

  float* zp = Z + (size_t)cell * (BB * GG * HH) + (size_t)g * HH + cid * 4;
#pragma unroll
  for (int j = 0; j < 4; ++j)
    *(float4*)(zp + (size_t)(bq * 4 + j) * (GG * HH)) = acc[j];
}

// Software-pipelined GEMV core. NM=2 (r0: Wt,Ws) or NM=3 (r1: Wt,Ws,U).
// Depth-2 ping-pong weight prefetch; fully unrolled over the 8 kk-steps.
template <int NM>
__device__ __forceinline__ void gemv_core(
    const float* __restrict__ wtp, const float* __restrict__ wsp,
    const float* __restrict__ wup, const float* xt, int ka0, int bq,
    float4 (&acc)[8]) {
  float4 wA[3][4], wB[3][4];

#define LW(W, KK) { \
    _Pragma("unroll") \
    for (int j = 0; j < 4; ++j) { \
      W[0][j] = *(const float4*)(wtp + (size_t)((KK) + j) * HH); \
      W[1][j] = *(const float4*)(wsp + (size_t)((KK) + j) * HH); \
      if (NM == 3) W[2][j] = *(const float4*)(wup + (size_t)((KK) + j) * HH); \
    } }

#define CP(W, KK) { \
    const int ka = ka0 + (KK); \
    _Pragma("unroll") \
    for (int i = 0; i < 8; ++i) { \
      const int b = bq + 4 * i; \
      float4 xT = *(const float4*)&xt[(0 * BB + b) * XPAD + ka]; \
      float4 xS = *(const float4*)&xt[(1 * BB + b) * XPAD + ka]; \
      float4 a = acc[i]; \
      fma4(a, W[0][0], xT.x); fma4(a, W[0][1], xT.y); \
      fma4(a, W[0][2], xT.z); fma4(a, W[0][3], xT.w); \
      fma4(a, W[1][0], xS.x); fma4(a, W[1][1], xS.y); \
      fma4(a, W[1][2], xS.z); fma4(a, W[1][3], xS.w); \
      if (NM == 3) { \
        float4 xU = *(const float4*)&xt[(2 * BB + b) * XPAD + ka]; \
        fma4(a, W[2][0], xU.x); fma4(a, W[2][1], xU.y); \
        fma4(a, W[2][2], xU.z); fma4(a, W[2][3], xU.w); \
      } \
      acc[i] = a; \
    } }

  LW(wA, 0)  LW(wB, 4)
  CP(wA, 0)  LW(wA, 8)
  CP(wB, 4)  LW(wB, 12)
  CP(wA, 8)  LW(wA, 16)
  CP(wB, 12) LW(wB, 20)
  CP(wA, 16) LW(wA, 24)
  CP(wB, 20) LW(wB, 28)
  CP(wA, 24)
  CP(wB, 28)
#undef LW
#undef CP
}

// One wavefront stage, gemv + fused combine. grid = cnt*10 (cell, gate, col-half),
// 256 threads. r0: Z += ht.Wt + hs.Ws (Z holds z0 = p.U+bias); r1: Z = h0.U + ht.Wt
// + hs.Ws + bias. The 10th slice-block to finish (ACQ_REL fetch_add) runs the
// gate-combine. No spin loops.
__global__ __launch_bounds__(256, 2)
void stage_fused(const float* __restrict__ U,
                 const float* __restrict__ Wt,
                 const float* __restrict__ Ws,
                 const float* __restrict__ bias,
                 const float* __restrict__ top_c,
                 const float* __restrict__ left_c,
                 const float* __restrict__ top_h0,
                 const float* __restrict__ top_h1,
                 const float* __restrict__ left_h,
                 float* __restrict__ h0, float* __restrict__ c0,
                 float* __restrict__ out_h, float* __restrict__ out_c,
                 float* __restrict__ Z,
                 int* __restrict__ zcnt,
                 StageList sl) {
  __shared__ __align__(16) float xt[3 * BB * XPAD];  // 50688 B
  __shared__ int s_old;

  const int cellIdx = blockIdx.x / 10;
  const int sub = blockIdx.x % 10;
  const int g = sub >> 1, ch = sub & 1;
  const int packed = sl.cells[cellIdx];
  const int r = (packed >> 16) & 0xff;
  const int f = (packed >> 8) & 0xff;
  const int n = packed & 0xff;
  const int cid = r * 200 + f * NBN + n;
  const int t = threadIdx.x;
  const int cellofs = f * FSTR + n * HH;

  // ---- stage x-vectors into LDS [b][k] (r0: 2 vecs; r1: 3) ----
  const float* hbase = r ? out_h : h0;
  const float* hp; int hbs;
  if (f > 0) { hp = hbase + cellofs - FSTR; hbs = BSTR; }
  else       { hp = (r ? top_h1 : top_h0) + n * HH; hbs = FSTR; }
  const float* lp; int lbs;
  if (n > 0) { lp = hbase + cellofs - HH; lbs = BSTR; }
  else       { lp = left_h + f * HH; lbs = FF * HH; }

  for (int i = t; i < BB * HH; i += 256) {
    int b = i >> 7, k = i & (HH - 1);
    xt[(0 * BB + b) * XPAD + k] = hp[(size_t)b * hbs + k];
    xt[(1 * BB + b) * XPAD + k] = lp[(size_t)b * lbs + k];
    if (r) xt[(2 * BB + b) * XPAD + k] = h0[(size_t)b * BSTR + cellofs + k];
  }
  __syncthreads();

  // ---- GEMV: thread = 4 cols x 8 batches, wave = k-quarter ----
  const int cg = t & 15, bq = (t >> 4) & 3, kh = t >> 6;
  const int col = ch * 64 + cg * 4;
  const size_t wofs = ((size_t)(r * FF + f) * NBN + n) * ((size_t)GG * HH * HH)
                    + (size_t)g * HH * HH + (size_t)(kh * 32) * HH + col;
  const float* wtp = Wt + wofs;
  const float* wsp = Ws + wofs;
  const float* wup = U + wofs;
  const int ka0 = kh * 32;

  float4 acc[8];
#pragma unroll
  for (int i = 0; i < 8; ++i) acc[i] = make_float4(0.f, 0.f, 0.f, 0.f);

  if (r) gemv_core<3>(wtp, wsp, wup, xt, ka0, bq, acc);
  else   gemv_core<2>(wtp, wsp, wup, xt, ka0, bq, acc);

  // ---- k-quarter reduce via LDS, then Z update ----
  __syncthreads();
  const int lane = t & 63;
  if (kh > 0) {
    float* rp = xt + (size_t)((kh - 1) * 64 + lane) * 36;
#pragma unroll
    for (int i = 0; i < 8; ++i) *(float4*)(rp + 4 * i) = acc[i];
  }
  __syncthreads();
  if (kh == 0) {
#pragma unroll
    for (int q = 0; q < 3; ++q) {
      const float* rp = xt + (size_t)(q * 64 + lane) * 36;
#pragma unroll
      for (int i = 0; i < 8; ++i) add4(acc[i], *(const float4*)(rp + 4 * i));
    }
    float* zbase = Z + (size_t)(f * NBN + n) * (BB * GG * HH) + (size_t)g * HH + col;
    if (r) {
      float4 bv = *(const float4*)(bias + (((size_t)(FF + f) * NBN + n) * GG + g) * HH + col);
#pragma unroll
      for (int i = 0; i < 8; ++i) {
        add4(acc[i], bv);
        *(float4*)(zbase + (size_t)(bq + 4 * i) * (GG * HH)) = acc[i];
      }
    } else {
#pragma unroll
      for (int i = 0; i < 8; ++i) {
        float4* dst = (float4*)(zbase + (size_t)(bq + 4 * i) * (GG * HH));
        float4 o = *dst; add4(o, acc[i]); *dst = o;
      }
    }
  }
  __syncthreads();

  // ---- spin-free rendezvous: the 10th finisher runs the combine ----
  if (t == 0)
    s_old = __hip_atomic_fetch_add(&zcnt[cid], 1, __ATOMIC_ACQ_REL, SC_SYS);
  __syncthreads();

  if (s_old == 9) {
    const int c = t & (HH - 1), bh = t >> 7;  // 2 halves x 16 batches
    float* hout = r ? out_h : h0;
    float* cout = r ? out_c : c0;
    const float* ctp; int ctbs;
    if (f > 0) { ctp = cout + cellofs - FSTR; ctbs = BSTR; }
    else       { ctp = top_c + n * HH; ctbs = FSTR; }
    const float* clp; int clbs;
    if (n > 0) { clp = cout + cellofs - HH; clbs = BSTR; }
    else       { clp = left_c + f * HH; clbs = FF * HH; }

    const float* zp = Z + (size_t)(f * NBN + n) * (BB * GG * HH) + c;
#pragma unroll
    for (int j = 0; j < 16; ++j) {
      const int b = bh * 16 + j;
      const float* zb = zp + (size_t)b * (GG * HH);
      float zi = zb[0], zfs = zb[HH], zft = zb[2 * HH], zo = zb[3 * HH], zc = zb[4 * HH];
      float clv = clp[(size_t)b * clbs + c];
      float ctv = ctp[(size_t)b * ctbs + c];
      float iv = sigm(zi), fsv = sigm(zfs), ftv = sigm(zft), ov = sigm(zo);
      float cn = tanh_fast(zc);
      float cnew = fmaf(iv, cn, fmaf(fsv, clv, ftv * ctv));
      float hnew = ov * tanh_fast(cnew);
      hout[(size_t)b * BSTR + cellofs + c] = hnew;
      cout[(size_t)b * BSTR + cellofs + c] = cnew;
    }
  }
}

extern "C" void kernel_launch(void* const* d_in, const int* in_sizes, int n_in,
                              void* d_out, int out_size, void* d_ws, size_t ws_size,
                              hipStream_t stream) {
  const float* hid  = (const float*)d_in[0];
  const float* cell = (const float*)d_in[1];
  const float* gt   = (const float*)d_in[2];
  // d_in[3] = global_s_state — dead for R=2
  const float* p    = (const float*)d_in[4];
  const float* U    = (const float*)d_in[5];
  const float* Wt   = (const float*)d_in[6];
  const float* Ws   = (const float*)d_in[7];
  const float* bias = (const float*)d_in[8];

  float* out_h = (float*)d_out;
  float* out_c = out_h + (size_t)BB * BSTR;

  float* w = (float*)d_ws;
  float* h0     = w; w += (size_t)BB * BSTR;
  float* c0     = w; w += (size_t)BB * BSTR;
  float* top_c  = w; w += (size_t)BB * NBN * HH;
  float* left_c = w; w += (size_t)BB * FF * HH;
  float* top_h0 = w; w += (size_t)BB * NBN * HH;
  float* top_h1 = w; w += (size_t)BB * NBN * HH;
  float* left_h = w; w += (size_t)BB * FF * HH;
  float* Z      = w; w += (size_t)FF * NBN * BB * GG * HH;  // 16.4 MB
  int* zcnt = (int*)w;  // [400]

  // zero rendezvous counters every call (ws not re-poisoned between replays)
  hipMemsetAsync(zcnt, 0, NCELLS * sizeof(int), stream);

  const int pre_threads = BB * NBN * HH + BB * FF * HH;
  hipLaunchKernelGGL(precompute_kernel, dim3((pre_threads + 255) / 256), dim3(256),
                     0, stream, hid, cell, gt, top_c, left_c, top_h0, top_h1, left_h);

  hipLaunchKernelGGL(z0_kernel, dim3(FF * NBN * GG), dim3(256), 0, stream,
                     p, U, bias, Z);

  // 30 wavefront stages: r0 cells at d=f+n, r1 cells at d=f+n+1
  for (int d = 0; d < FF + NBN; ++d) {
    StageList sl; sl.cnt = 0;
    for (int r = 0; r < 2; ++r) {
      int dd = d - r;
      for (int f = 0; f < FF; ++f) {
        int n = dd - f;
        if (n >= 0 && n < NBN) sl.cells[sl.cnt++] = (r << 16) | (f << 8) | n;
      }
    }
    if (sl.cnt == 0) continue;
    hipLaunchKernelGGL(stage_fused, dim3(sl.cnt * 10), dim3(256), 0, stream,
                       U, Wt, Ws, bias, top_c, left_c, top_h0, top_h1, left_h,
                       h0, c0, out_h, out_c, Z, zcnt, sl);
  }
}

// Round 11
// 839.721 us; speedup vs baseline: 1.1326x; 1.1326x over previous
//
#include <hip/hip_runtime.h>
#include <cstdint>
#include <cstddef>

#define BB  32
#define FF  10
#define NBN 20
#define HH  128
#define GG  5
#define BSTR (FF*NBN*HH)   // 25600
#define FSTR (NBN*HH)      // 2560
#define XPAD 132           // LDS [b][k] row stride (floats)
#define NCELLS 400
#define WELEM 32768000     // elems per weight tensor: 2*10*20*5*128*128
#define SC_SYS __HIP_MEMORY_SCOPE_SYSTEM

struct StageList { int cnt; int cells[20]; };  // packed (r<<16)|(f<<8)|n

__device__ __forceinline__ float sigm(float x) {
  return 1.f / (1.f + __expf(-x));
}
__device__ __forceinline__ float tanh_fast(float x) {
  float e = __expf(-2.f * fabsf(x));
  float t = (1.f - e) / (1.f + e);
  return copysignf(t, x);
}
__device__ __forceinline__ void fma4(float4& a, const float4 w, const float h) {
  a.x = fmaf(w.x, h, a.x); a.y = fmaf(w.y, h, a.y);
  a.z = fmaf(w.z, h, a.z); a.w = fmaf(w.w, h, a.w);
}
__device__ __forceinline__ void add4(float4& a, const float4 b) {
  a.x += b.x; a.y += b.y; a.z += b.z; a.w += b.w;
}
// 4 bf16 weights (8 B) -> float4
__device__ __forceinline__ float4 ldw(const unsigned short* p) {
  uint2 u = *(const uint2*)p;
  float4 r;
  r.x = __uint_as_float(u.x << 16);
  r.y = __uint_as_float(u.x & 0xffff0000u);
  r.z = __uint_as_float(u.y << 16);
  r.w = __uint_as_float(u.y & 0xffff0000u);
  return r;
}
__device__ __forceinline__ unsigned int bf16_rtn(float f) {
  unsigned int u = __float_as_uint(f);
  return (u + 0x7FFFu + ((u >> 16) & 1u)) >> 16;
}

// fp32 -> bf16 weight conversion (RTN). grid = 3*16000 blocks, 256 thr, 8 elem/thr.
__global__ __launch_bounds__(256)
void convert_kernel(const float* __restrict__ U, const float* __restrict__ Wt,
                    const float* __restrict__ Ws,
                    unsigned short* __restrict__ Ub, unsigned short* __restrict__ Wtb,
                    unsigned short* __restrict__ Wsb) {
  const int per = WELEM / 2048;  // 16000
  const int a = blockIdx.x / per, bo = blockIdx.x % per;
  const float* src = (a == 0) ? U : (a == 1) ? Wt : Ws;
  unsigned short* dst = (a == 0) ? Ub : (a == 1) ? Wtb : Wsb;
  const size_t base = ((size_t)bo * 256 + threadIdx.x) * 8;
  float4 v0 = *(const float4*)(src + base);
  float4 v1 = *(const float4*)(src + base + 4);
  uint4 o;
  o.x = bf16_rtn(v0.x) | (bf16_rtn(v0.y) << 16);
  o.y = bf16_rtn(v0.z) | (bf16_rtn(v0.w) << 16);
  o.z = bf16_rtn(v1.x) | (bf16_rtn(v1.y) << 16);
  o.w = bf16_rtn(v1.z) | (bf16_rtn(v1.w) << 16);
  *(uint4*)(dst + base) = o;
}

// Boundary vectors (pure functions of inputs).
__global__ void precompute_kernel(
    const float* __restrict__ hid, const float* __restrict__ cell,
    const float* __restrict__ gt,
    float* __restrict__ top_c, float* __restrict__ left_c,
    float* __restrict__ top_h0, float* __restrict__ top_h1,
    float* __restrict__ left_h) {
  int idx = blockIdx.x * 256 + threadIdx.x;
  const int NTOP = BB * NBN * HH;
  const int NLEFT = BB * FF * HH;
  if (idx < NTOP) {
    int h = idx & (HH - 1);
    int n = (idx >> 7) % NBN;
    int b = idx / (HH * NBN);
    const float* hp = hid + (size_t)b * BSTR + n * HH + h;
    const float* cp = cell + (size_t)b * BSTR + n * HH + h;
    float sh = 0.f, sc = 0.f;
#pragma unroll
    for (int f = 0; f < FF; ++f) { sh += hp[f * FSTR]; sc += cp[f * FSTR]; }
    top_c[idx]  = sc * (1.f / FF);
    top_h0[idx] = sh * (1.f / FF);
    top_h1[idx] = (sh + gt[idx]) * (1.f / (FF + 1));
  } else if (idx < NTOP + NLEFT) {
    int j = idx - NTOP;
    int h = j & (HH - 1);
    int f = (j >> 7) % FF;
    int b = j / (HH * FF);
    const float* hp = hid + (size_t)b * BSTR + f * FSTR + h;
    const float* cp = cell + (size_t)b * BSTR + f * FSTR + h;
    float sh = 0.f, sc = 0.f;
#pragma unroll
    for (int n = 0; n < NBN; ++n) { sh += hp[n * HH]; sc += cp[n * HH]; }
    left_c[j] = sc * (1.f / NBN);
    left_h[j] = sh * (1.f / NBN);
  }
}

// Z0 = p.U[0](bf16) + bias[0] — dependency-free. grid = 1000 blocks, 256 threads.
__global__ __launch_bounds__(256, 4)
void z0_kernel(const float* __restrict__ p, const unsigned short* __restrict__ Ub,
               const float* __restrict__ bias, float* __restrict__ Z) {
  __shared__ __align__(16) float xs[HH][36];
  const int cell = blockIdx.x / GG, g = blockIdx.x % GG;
  const int f = cell / NBN, n = cell % NBN;
  const int t = threadIdx.x;
  const int cid = t & 31, bq = t >> 5;
  const int cellofs = f * FSTR + n * HH;

  for (int i = t; i < BB * HH; i += 256) {
    int b = i >> 7, k = i & (HH - 1);
    xs[k][b] = p[(size_t)b * BSTR + cellofs + k];
  }
  __syncthreads();

  const unsigned short* wu = Ub + (size_t)cell * (GG * HH * HH)
                           + (size_t)g * HH * HH + cid * 4;
  float4 bv = *(const float4*)(bias + (size_t)cell * (GG * HH) + g * HH + cid * 4);
  float4 acc[4];
#pragma unroll
  for (int j = 0; j < 4; ++j) acc[j] = bv;

#pragma unroll 4
  for (int k = 0; k < HH; ++k) {
    float4 w = ldw(wu + (size_t)k * HH);
    float4 x = *(const float4*)&xs[k][bq * 4];
    fma4(acc[0], w, x.x); fma4(acc[1], w, x.y);
    fma4(acc[2], w, x.z); fma4(acc[3], w, x.w);
  }

  float* zp = Z + (size_t)cell * (BB * GG * HH) + (size_t)g * HH + cid * 4;
#pragma unroll
  for (int j = 0; j < 4; ++j)
    *(float4*)(zp + (size_t)(bq * 4 + j) * (GG * HH)) = acc[j];
}

// Simple (compiler-scheduled) GEMV core. NM=2 (r0: Wt,Ws) or NM=3 (r1: +U).
template <int NM>
__device__ __forceinline__ void gemv_core(
    const unsigned short* __restrict__ wtp, const unsigned short* __restrict__ wsp,
    const unsigned short* __restrict__ wup, const float* xt, int ka0, int bq,
    float4 (&acc)[4]) {
  for (int kk = 0; kk < 32; kk += 4) {
    float4 wT[4], wS[4], wU[4];
#pragma unroll
    for (int j = 0; j < 4; ++j) {
      wT[j] = ldw(wtp + (size_t)(kk + j) * HH);
      wS[j] = ldw(wsp + (size_t)(kk + j) * HH);
      if (NM == 3) wU[j] = ldw(wup + (size_t)(kk + j) * HH);
    }
    const int ka = ka0 + kk;
#pragma unroll
    for (int i = 0; i < 4; ++i) {
      const int b = bq + 8 * i;
      float4 xT = *(const float4*)&xt[(0 * BB + b) * XPAD + ka];
      float4 xS = *(const float4*)&xt[(1 * BB + b) * XPAD + ka];
      float4 a = acc[i];
      fma4(a, wT[0], xT.x); fma4(a, wT[1], xT.y); fma4(a, wT[2], xT.z); fma4(a, wT[3], xT.w);
      fma4(a, wS[0], xS.x); fma4(a, wS[1], xS.y); fma4(a, wS[2], xS.z); fma4(a, wS[3], xS.w);
      if (NM == 3) {
        float4 xU = *(const float4*)&xt[(2 * BB + b) * XPAD + ka];
        fma4(a, wU[0], xU.x); fma4(a, wU[1], xU.y); fma4(a, wU[2], xU.z); fma4(a, wU[3], xU.w);
      }
      acc[i] = a;
    }
  }
}

// One wavefront stage, gemv + fused combine. grid = cnt*10 (cell, gate, col-half),
// 512 threads (8 waves = 2/SIMD). Thread: cg=t&15 (4 cols), bq=(t>>4)&7 (4 batches
// b=bq+8i), kh=t>>7 (wave-pair = k-quarter). r0: Z += ht.Wt + hs.Ws (Z holds z0);
// r1: Z = h0.U + ht.Wt + hs.Ws + bias. The 10th slice-block finisher (ACQ_REL
// fetch_add, system scope) runs the gate-combine. No spin loops.
__global__ __launch_bounds__(512, 2)
void stage_fused(const unsigned short* __restrict__ Ub,
                 const unsigned short* __restrict__ Wtb,
                 const unsigned short* __restrict__ Wsb,
                 const float* __restrict__ bias,
                 const float* __restrict__ top_c,
                 const float* __restrict__ left_c,
                 const float* __restrict__ top_h0,
                 const float* __restrict__ top_h1,
                 const float* __restrict__ left_h,
                 float* __restrict__ h0, float* __restrict__ c0,
                 float* __restrict__ out_h, float* __restrict__ out_c,
                 float* __restrict__ Z,
                 int* __restrict__ zcnt,
                 StageList sl) {
  __shared__ __align__(16) float xt[3 * BB * XPAD];  // 50688 B; reused as reduce buf
  __shared__ int s_old;

  const int cellIdx = blockIdx.x / 10;
  const int sub = blockIdx.x % 10;
  const int g = sub >> 1, ch = sub & 1;
  const int packed = sl.cells[cellIdx];
  const int r = (packed >> 16) & 0xff;
  const int f = (packed >> 8) & 0xff;
  const int n = packed & 0xff;
  const int cid = r * 200 + f * NBN + n;
  const int t = threadIdx.x;
  const int cellofs = f * FSTR + n * HH;

  // ---- stage x-vectors into LDS [b][k] (r0: 2 vecs; r1: 3) ----
  const float* hbase = r ? out_h : h0;
  const float* hp; int hbs;
  if (f > 0) { hp = hbase + cellofs - FSTR; hbs = BSTR; }
  else       { hp = (r ? top_h1 : top_h0) + n * HH; hbs = FSTR; }
  const float* lp; int lbs;
  if (n > 0) { lp = hbase + cellofs - HH; lbs = BSTR; }
  else       { lp = left_h + f * HH; lbs = FF * HH; }

  for (int i = t; i < BB * HH; i += 512) {
    int b = i >> 7, k = i & (HH - 1);
    xt[(0 * BB + b) * XPAD + k] = hp[(size_t)b * hbs + k];
    xt[(1 * BB + b) * XPAD + k] = lp[(size_t)b * lbs + k];
    if (r) xt[(2 * BB + b) * XPAD + k] = h0[(size_t)b * BSTR + cellofs + k];
  }
  __syncthreads();

  // ---- GEMV ----
  const int cg = t & 15, bq = (t >> 4) & 7, kh = t >> 7;
  const int col = ch * 64 + cg * 4;
  const size_t wofs = ((size_t)(r * FF + f) * NBN + n) * ((size_t)GG * HH * HH)
                    + (size_t)g * HH * HH + (size_t)(kh * 32) * HH + col;
  const unsigned short* wtp = Wtb + wofs;
  const unsigned short* wsp = Wsb + wofs;
  const unsigned short* wup = Ub + wofs;
  const int ka0 = kh * 32;

  float4 acc[4];
#pragma unroll
  for (int i = 0; i < 4; ++i) acc[i] = make_float4(0.f, 0.f, 0.f, 0.f);

  if (r) gemv_core<3>(wtp, wsp, wup, xt, ka0, bq, acc);
  else   gemv_core<2>(wtp, wsp, wup, xt, ka0, bq, acc);

  // ---- k-quarter reduce via LDS (xt reused), then Z update ----
  __syncthreads();
  const int pair = bq * 16 + cg;  // 0..127
  if (kh > 0) {
    float* rp = xt + (size_t)((kh - 1) * 128 + pair) * 20;
#pragma unroll
    for (int i = 0; i < 4; ++i) *(float4*)(rp + 4 * i) = acc[i];
  }
  __syncthreads();
  if (kh == 0) {
#pragma unroll
    for (int q = 0; q < 3; ++q) {
      const float* rp = xt + (size_t)(q * 128 + pair) * 20;
#pragma unroll
      for (int i = 0; i < 4; ++i) add4(acc[i], *(const float4*)(rp + 4 * i));
    }
    float* zbase = Z + (size_t)(f * NBN + n) * (BB * GG * HH) + (size_t)g * HH + col;
    if (r) {
      float4 bv = *(const float4*)(bias + (((size_t)(FF + f) * NBN + n) * GG + g) * HH + col);
#pragma unroll
      for (int i = 0; i < 4; ++i) {
        add4(acc[i], bv);
        *(float4*)(zbase + (size_t)(bq + 8 * i) * (GG * HH)) = acc[i];
      }
    } else {
#pragma unroll
      for (int i = 0; i < 4; ++i) {
        float4* dst = (float4*)(zbase + (size_t)(bq + 8 * i) * (GG * HH));
        float4 o = *dst; add4(o, acc[i]); *dst = o;
      }
    }
  }
  __syncthreads();

  // ---- spin-free rendezvous: the 10th finisher runs the combine ----
  if (t == 0)
    s_old = __hip_atomic_fetch_add(&zcnt[cid], 1, __ATOMIC_ACQ_REL, SC_SYS);
  __syncthreads();

  if (s_old == 9) {
    const int c = t & (HH - 1), bh = t >> 7;  // 4 groups x 8 batches
    float* hout = r ? out_h : h0;
    float* cout = r ? out_c : c0;
    const float* ctp; int ctbs;
    if (f > 0) { ctp = cout + cellofs - FSTR; ctbs = BSTR; }
    else       { ctp = top_c + n * HH; ctbs = FSTR; }
    const float* clp; int clbs;
    if (n > 0) { clp = cout + cellofs - HH; clbs = BSTR; }
    else       { clp = left_c + f * HH; clbs = FF * HH; }

    const float* zp = Z + (size_t)(f * NBN + n) * (BB * GG * HH) + c;
#pragma unroll
    for (int j = 0; j < 8; ++j) {
      const int b = bh * 8 + j;
      const float* zb = zp + (size_t)b * (GG * HH);
      float zi = zb[0], zfs = zb[HH], zft = zb[2 * HH], zo = zb[3 * HH], zc = zb[4 * HH];
      float clv = clp[(size_t)b * clbs + c];
      float ctv = ctp[(size_t)b * ctbs + c];
      float iv = sigm(zi), fsv = sigm(zfs), ftv = sigm(zft), ov = sigm(zo);
      float cn = tanh_fast(zc);
      float cnew = fmaf(iv, cn, fmaf(fsv, clv, ftv * ctv));
      float hnew = ov * tanh_fast(cnew);
      hout[(size_t)b * BSTR + cellofs + c] = hnew;
      cout[(size_t)b * BSTR + cellofs + c] = cnew;
    }
  }
}

extern "C" void kernel_launch(void* const* d_in, const int* in_sizes, int n_in,
                              void* d_out, int out_size, void* d_ws, size_t ws_size,
                              hipStream_t stream) {
  const float* hid  = (const float*)d_in[0];
  const float* cell = (const float*)d_in[1];
  const float* gt   = (const float*)d_in[2];
  // d_in[3] = global_s_state — dead for R=2
  const float* p    = (const float*)d_in[4];
  const float* U    = (const float*)d_in[5];
  const float* Wt   = (const float*)d_in[6];
  const float* Ws   = (const float*)d_in[7];
  const float* bias = (const float*)d_in[8];

  float* out_h = (float*)d_out;
  float* out_c = out_h + (size_t)BB * BSTR;

  float* w = (float*)d_ws;
  float* h0     = w; w += (size_t)BB * BSTR;
  float* c0     = w; w += (size_t)BB * BSTR;
  float* top_c  = w; w += (size_t)BB * NBN * HH;
  float* left_c = w; w += (size_t)BB * FF * HH;
  float* top_h0 = w; w += (size_t)BB * NBN * HH;
  float* top_h1 = w; w += (size_t)BB * NBN * HH;
  float* left_h = w; w += (size_t)BB * FF * HH;
  float* Z      = w; w += (size_t)FF * NBN * BB * GG * HH;  // 16.4 MB
  int* zcnt = (int*)w; w += 512;                            // [400] + pad
  unsigned short* Ub  = (unsigned short*)w;                 // 3 x 65.5 MB bf16
  unsigned short* Wtb = Ub + (size_t)WELEM;
  unsigned short* Wsb = Wtb + (size_t)WELEM;

  // zero rendezvous counters every call (ws not re-poisoned between replays)
  hipMemsetAsync(zcnt, 0, NCELLS * sizeof(int), stream);

  hipLaunchKernelGGL(convert_kernel, dim3(3 * (WELEM / 2048)), dim3(256), 0, stream,
                     U, Wt, Ws, Ub, Wtb, Wsb);

  const int pre_threads = BB * NBN * HH + BB * FF * HH;
  hipLaunchKernelGGL(precompute_kernel, dim3((pre_threads + 255) / 256), dim3(256),
                     0, stream, hid, cell, gt, top_c, left_c, top_h0, top_h1, left_h);

  hipLaunchKernelGGL(z0_kernel, dim3(FF * NBN * GG), dim3(256), 0, stream,
                     p, Ub, bias, Z);

  // 30 wavefront stages: r0 cells at d=f+n, r1 cells at d=f+n+1
  for (int d = 0; d < FF + NBN; ++d) {
    StageList sl; sl.cnt = 0;
    for (int r = 0; r < 2; ++r) {
      int dd = d - r;
      for (int f = 0; f < FF; ++f) {
        int n = dd - f;
        if (n >= 0 && n < NBN) sl.cells[sl.cnt++] = (r << 16) | (f << 8) | n;
      }
    }
    if (sl.cnt == 0) continue;
    hipLaunchKernelGGL(stage_fused, dim3(sl.cnt * 10), dim3(512), 0, stream,
                       Ub, Wtb, Wsb, bias, top_c, left_c, top_h0, top_h1, left_h,
                       h0, c0, out_h, out_c, Z, zcnt, sl);
  }
}